// Round 1
// baseline (164.178 us; speedup 1.0000x reference)
//
#include <hip/hip_runtime.h>

#define Bq 1024
#define NINq 2048
#define Hq 2048
#define NOUTq 512

#define DECAYF 0.95122942450071400910f
#define THRF 0.4f

// d_out offsets (in floats), outputs concatenated in return order
#define OFF_OUT  0
#define OFF_Z    524288
#define OFF_V    2621440
#define OFF_R    4718592
#define OFF_TIN  6815744
#define OFF_TREC 8912896
#define OFF_DZ   11010048

typedef __attribute__((ext_vector_type(8))) short  bf16x8;
typedef __attribute__((ext_vector_type(4))) short  s16x4;
typedef __attribute__((ext_vector_type(4))) float  f32x4;

__device__ __forceinline__ unsigned short cvt_bf16(float f) {
  unsigned u = __float_as_uint(f);
  return (unsigned short)((u + 0x7FFFu + ((u >> 16) & 1u)) >> 16);
}

// MODE 0: i_t = inputs@w_in + z@w_rec (hi/lo split), fused LIF epilogue.
//         M=1024 N=2048 K=4096(eff), BM=64 BN=128 -> grid 16x16 = 256 WGs.
// MODE 1: new_out = kappa*out + new_z@w_out (single bf16 weights).
//         M=1024 N=512 K=2048, BM=32 BN=64 -> grid 8x32 = 256 WGs.
template<int MODE>
__global__ __launch_bounds__(256, 1)
void fused_gemm(const float* __restrict__ A0g, const float* __restrict__ A1g,
                const float* __restrict__ W0g, const float* __restrict__ W1g,
                const float* __restrict__ e0, const float* __restrict__ e1,
                const float* __restrict__ e2, float* __restrict__ dout)
{
  constexpr int BM = (MODE == 0) ? 64 : 32;
  constexpr int BN = (MODE == 0) ? 128 : 64;
  constexpr int BK = 64;
  constexpr int LDA = BK + 8;                 // +8 bf16 pad: 144B rows, b128 reads 2-way max
  constexpr int MR = (MODE == 0) ? 2 : 1;     // 16x16 frags per wave (M)
  constexpr int NR = (MODE == 0) ? 4 : 2;     // 16x16 frags per wave (N)
  constexpr int WM = MR * 16, WN = NR * 16;
  constexpr int KT = (MODE == 0) ? 64 : 32;   // K-steps of 64
  constexpr int Nmat = (MODE == 0) ? Hq : NOUTq;
  constexpr int QA = BM / 16;                 // A stage passes
  constexpr int QW = (16 * BN) / 256;         // W stage passes
  constexpr int KSH = (MODE == 0) ? 7 : 6;
  constexpr int KSTEP = (MODE == 0) ? 2 : 4;

  __shared__ __align__(16) short As[BM * LDA];
  __shared__ __align__(16) short Wh[BN * LDA];                         // W^T hi, [n][k]
  __shared__ __align__(16) short Wl[((MODE == 0) ? BN : 1) * LDA];     // W^T lo

  const int tid  = threadIdx.x;
  const int lane = tid & 63;
  const int wave = tid >> 6;
  const int lr = lane & 15, hl = lane >> 4;
  const int wmOff = (wave >> 1) * WM;
  const int wnOff = (wave & 1) * WN;
  const int m0 = blockIdx.y * BM;
  const int n0 = blockIdx.x * BN;
  const int arow = tid >> 4, ac4 = tid & 15;
  const int wn = tid & (BN - 1);

  f32x4 aR[QA];        // prefetched A (f32)
  float wR[QW][4];     // prefetched W columns (4 k's at fixed n)
  f32x4 acc[MR][NR];
#pragma unroll
  for (int mi = 0; mi < MR; ++mi)
#pragma unroll
    for (int ni = 0; ni < NR; ++ni)
      acc[mi][ni] = (f32x4){0.f, 0.f, 0.f, 0.f};

  auto LOAD = [&](int kt) {
    const float* Ag = A0g; const float* Wg = W0g; int k0 = kt * BK;
    if (MODE == 0 && kt >= 32) { Ag = A1g; Wg = W1g; k0 = (kt - 32) * BK; }
#pragma unroll
    for (int q = 0; q < QA; ++q)
      aR[q] = *(const f32x4*)&Ag[(m0 + arow + q * 16) * 2048 + k0 + ac4 * 4];
#pragma unroll
    for (int p = 0; p < QW; ++p) {
      const int kq = (tid >> KSH) + p * KSTEP;
#pragma unroll
      for (int i = 0; i < 4; ++i)
        wR[p][i] = Wg[(k0 + kq * 4 + i) * Nmat + n0 + wn];
    }
  };

  auto STORE = [&]() {
#pragma unroll
    for (int q = 0; q < QA; ++q) {
      s16x4 hv;
#pragma unroll
      for (int j = 0; j < 4; ++j) hv[j] = (short)cvt_bf16(aR[q][j]);
      *(s16x4*)&As[(arow + q * 16) * LDA + ac4 * 4] = hv;
    }
#pragma unroll
    for (int p = 0; p < QW; ++p) {
      const int kq = (tid >> KSH) + p * KSTEP;
      s16x4 hh, ll;
#pragma unroll
      for (int i = 0; i < 4; ++i) {
        const float w = wR[p][i];
        const unsigned short h = cvt_bf16(w);
        hh[i] = (short)h;
        if (MODE == 0) {
          const float hf = __uint_as_float(((unsigned)h) << 16);
          ll[i] = (short)cvt_bf16(w - hf);   // exact residual -> bf16
        }
      }
      *(s16x4*)&Wh[wn * LDA + kq * 4] = hh;
      if (MODE == 0) *(s16x4*)&Wl[wn * LDA + kq * 4] = ll;
    }
  };

  LOAD(0);
  for (int kt = 0; kt < KT; ++kt) {
    __syncthreads();
    STORE();
    __syncthreads();
    if (kt + 1 < KT) LOAD(kt + 1);   // next-tile globals overlap MFMA phase
#pragma unroll
    for (int ks = 0; ks < 2; ++ks) {
      bf16x8 af[MR];
#pragma unroll
      for (int mi = 0; mi < MR; ++mi)
        af[mi] = *(const bf16x8*)&As[(wmOff + mi * 16 + lr) * LDA + ks * 32 + hl * 8];
#pragma unroll
      for (int ni = 0; ni < NR; ++ni) {
        const bf16x8 bh = *(const bf16x8*)&Wh[(wnOff + ni * 16 + lr) * LDA + ks * 32 + hl * 8];
#pragma unroll
        for (int mi = 0; mi < MR; ++mi)
          acc[mi][ni] = __builtin_amdgcn_mfma_f32_16x16x32_bf16(af[mi], bh, acc[mi][ni], 0, 0, 0);
        if (MODE == 0) {
          const bf16x8 bl = *(const bf16x8*)&Wl[(wnOff + ni * 16 + lr) * LDA + ks * 32 + hl * 8];
#pragma unroll
          for (int mi = 0; mi < MR; ++mi)
            acc[mi][ni] = __builtin_amdgcn_mfma_f32_16x16x32_bf16(af[mi], bl, acc[mi][ni], 0, 0, 0);
        }
      }
    }
  }

  // ---- fused epilogue ----  C/D frag layout: col = lane&15, row = (lane>>4)*4 + reg
#pragma unroll
  for (int mi = 0; mi < MR; ++mi) {
#pragma unroll
    for (int ni = 0; ni < NR; ++ni) {
#pragma unroll
      for (int j = 0; j < 4; ++j) {
        const int m = m0 + wmOff + mi * 16 + hl * 4 + j;
        const int n = n0 + wnOff + ni * 16 + lr;
        if (MODE == 0) {
          const int idx = m * Hq + n;
          const float it = acc[mi][ni][j];
          const float vold = e0[idx];
          const float zold = e1[idx];
          const float rold = e2[idx];
          const float nv = DECAYF * vold + it - zold * THRF;
          const float vs = (nv - THRF) / THRF;
          const bool refr = rold > 0.1f;
          const float nz = (refr || !(vs > 0.0f)) ? 0.0f : 1.0f;
          const float nr = fminf(fmaxf(rold + 5.0f * nz - 1.0f, 0.0f), 5.0f);
          const float dz = refr ? 0.0f : (fmaxf(0.3f * (1.0f - fabsf(vs)), 0.0f) / THRF);
          dout[OFF_V + idx] = nv;
          dout[OFF_Z + idx] = nz;
          dout[OFF_R + idx] = nr;
          dout[OFF_DZ + idx] = dz;
        } else {
          const int idx = m * NOUTq + n;
          dout[OFF_OUT + idx] = DECAYF * e0[idx] + acc[mi][ni][j];
        }
      }
    }
  }
}

__global__ __launch_bounds__(256)
void trace_kernel(const float4* __restrict__ tin, const float4* __restrict__ ins,
                  const float4* __restrict__ trec, const float4* __restrict__ zin,
                  float4* __restrict__ o1, float4* __restrict__ o2)
{
  const int n4 = (Bq * NINq) / 4;
  for (int i = blockIdx.x * blockDim.x + threadIdx.x; i < n4; i += gridDim.x * blockDim.x) {
    const float4 a = tin[i], b = ins[i];
    float4 u;
    u.x = a.x * DECAYF + b.x; u.y = a.y * DECAYF + b.y;
    u.z = a.z * DECAYF + b.z; u.w = a.w * DECAYF + b.w;
    o1[i] = u;
    const float4 c = trec[i], d = zin[i];
    float4 w;
    w.x = c.x * DECAYF + d.x; w.y = c.y * DECAYF + d.y;
    w.z = c.z * DECAYF + d.z; w.w = c.w * DECAYF + d.w;
    o2[i] = w;
  }
}

extern "C" void kernel_launch(void* const* d_in, const int* in_sizes, int n_in,
                              void* d_out, int out_size, void* d_ws, size_t ws_size,
                              hipStream_t stream) {
  const float* inputs = (const float*)d_in[0];
  const float* v      = (const float*)d_in[1];
  const float* z      = (const float*)d_in[2];
  const float* r      = (const float*)d_in[3];
  const float* outp   = (const float*)d_in[4];
  const float* tin    = (const float*)d_in[5];
  const float* trec   = (const float*)d_in[6];
  const float* w_in   = (const float*)d_in[7];
  const float* w_rec  = (const float*)d_in[8];
  const float* w_out  = (const float*)d_in[9];
  float* out = (float*)d_out;

  trace_kernel<<<2048, 256, 0, stream>>>((const float4*)tin, (const float4*)inputs,
                                         (const float4*)trec, (const float4*)z,
                                         (float4*)(out + OFF_TIN), (float4*)(out + OFF_TREC));
  // i_t GEMM + LIF epilogue (writes new_z/new_v/new_r/dz_dh)
  fused_gemm<0><<<dim3(16, 16), 256, 0, stream>>>(inputs, z, w_in, w_rec, v, z, r, out);
  // new_out = kappa*out + new_z @ w_out  (reads new_z from d_out, stream-ordered)
  fused_gemm<1><<<dim3(8, 32), 256, 0, stream>>>(out + OFF_Z, nullptr, w_out, nullptr,
                                                 outp, nullptr, nullptr, out);
}

// Round 3
// 93.631 us; speedup vs baseline: 1.7535x; 1.7535x over previous
//
#include <hip/hip_runtime.h>

#define Bq 1024
#define Hq 2048
#define NOUTq 512

#define DECAYF 0.95122942450071400910f
#define THRF 0.4f

// d_out offsets (in floats), outputs concatenated in return order
#define OFF_OUT  0
#define OFF_Z    524288
#define OFF_V    2621440
#define OFF_R    4718592
#define OFF_TIN  6815744
#define OFF_TREC 8912896
#define OFF_DZ   11010048

// ws layout (bytes)
#define WS_ACOMB 0ul           // bf16 [1024][4096]  (inputs | z)        8 MB
#define WS_WHI   8388608ul     // bf16 W^T hi [2048][4096]              16 MB
#define WS_WLO   25165824ul    // bf16 W^T lo [2048][4096]              16 MB
#define WS_WOUTT 41943040ul    // bf16 w_out^T [512][2048]               2 MB
#define WS_P     44040192ul    // f32 partials [4][1024][2048]          32 MB
#define WS_Z2    77594624ul    // bf16 new_z [1024][2048]                4 MB
#define WS_NEED  81788928ul

typedef __attribute__((ext_vector_type(8))) short  bf16x8;
typedef __attribute__((ext_vector_type(4))) short  s16x4;
typedef __attribute__((ext_vector_type(4))) float  f32x4;

__device__ __forceinline__ unsigned short cvt_bf16(float f) {
  unsigned u = __float_as_uint(f);
  return (unsigned short)((u + 0x7FFFu + ((u >> 16) & 1u)) >> 16);
}

__device__ __forceinline__ void gl_lds16(const void* g, void* l) {
  __builtin_amdgcn_global_load_lds((const __attribute__((address_space(1))) unsigned int*)g,
                                   (__attribute__((address_space(3))) unsigned int*)l, 16, 0, 0);
}

// ---------------- fast path ----------------

// traces + pack A = [inputs | z] as bf16 [1024][4096]
__global__ __launch_bounds__(256)
void trace_convA(const f32x4* __restrict__ tin, const f32x4* __restrict__ ins,
                 const f32x4* __restrict__ trec, const f32x4* __restrict__ zin,
                 f32x4* __restrict__ o1, f32x4* __restrict__ o2, short* __restrict__ Acomb)
{
  const int i = blockIdx.x * 256 + threadIdx.x;          // 2048 blocks x 256 = exact
  const f32x4 b = ins[i];
  const f32x4 d = zin[i];
  o1[i] = tin[i] * DECAYF + b;
  o2[i] = trec[i] * DECAYF + d;
  const int e = i * 4, m = e >> 11, k = e & 2047;
  s16x4 ab, zb;
#pragma unroll
  for (int j = 0; j < 4; ++j) { ab[j] = (short)cvt_bf16(b[j]); zb[j] = (short)cvt_bf16(d[j]); }
  *(s16x4*)&Acomb[m * 4096 + k] = ab;
  *(s16x4*)&Acomb[m * 4096 + 2048 + k] = zb;
}

// transpose + split weights: Whi/Wlo [n=2048][k=4096], WoutT [n=512][k=2048]
__global__ __launch_bounds__(256)
void convW(const float* __restrict__ w_in, const float* __restrict__ w_rec,
           const float* __restrict__ w_out, short* __restrict__ Whi,
           short* __restrict__ Wlo, short* __restrict__ WoutT)
{
  __shared__ float tile[64][65];
  const int tid = threadIdx.x;
  const int rr = tid >> 4, c4 = (tid & 15) * 4;
  const int bx = blockIdx.x;
  if (bx < 2048) {                                       // w_in|w_rec, combined k 0..4095
    const int k0 = (bx >> 5) * 64, n0 = (bx & 31) * 64;
#pragma unroll
    for (int p = 0; p < 4; ++p) {
      const int kk = p * 16 + rr, kg = k0 + kk;
      const float* src = (kg < 2048) ? &w_in[kg * 2048 + n0 + c4]
                                     : &w_rec[(kg - 2048) * 2048 + n0 + c4];
      const f32x4 v = *(const f32x4*)src;
#pragma unroll
      for (int j = 0; j < 4; ++j) tile[kk][c4 + j] = v[j];
    }
    __syncthreads();
#pragma unroll
    for (int p = 0; p < 4; ++p) {
      const int nn = p * 16 + rr;
      s16x4 hh, ll;
#pragma unroll
      for (int j = 0; j < 4; ++j) {
        const float w = tile[c4 + j][nn];
        const unsigned short h = cvt_bf16(w);
        hh[j] = (short)h;
        ll[j] = (short)cvt_bf16(w - __uint_as_float(((unsigned)h) << 16));
      }
      *(s16x4*)&Whi[(n0 + nn) * 4096 + k0 + c4] = hh;
      *(s16x4*)&Wlo[(n0 + nn) * 4096 + k0 + c4] = ll;
    }
  } else {                                               // w_out [2048][512] -> WoutT
    const int b2 = bx - 2048;
    const int k0 = (b2 >> 3) * 64, n0 = (b2 & 7) * 64;
#pragma unroll
    for (int p = 0; p < 4; ++p) {
      const int kk = p * 16 + rr;
      const f32x4 v = *(const f32x4*)&w_out[(k0 + kk) * 512 + n0 + c4];
#pragma unroll
      for (int j = 0; j < 4; ++j) tile[kk][c4 + j] = v[j];
    }
    __syncthreads();
#pragma unroll
    for (int p = 0; p < 4; ++p) {
      const int nn = p * 16 + rr;
      s16x4 hh;
#pragma unroll
      for (int j = 0; j < 4; ++j) hh[j] = (short)cvt_bf16(tile[c4 + j][nn]);
      *(s16x4*)&WoutT[(n0 + nn) * 2048 + k0 + c4] = hh;
    }
  }
}

// MODE 0: P[kz] = Acomb(1024x4096 slice) @ W^T(hi)+W^T(lo), 128x128 tile, K-split 4.
//         grid 512 (1D, XCD-chunk swizzled), f32 partials to ws.
// MODE 1: new_out = kappa*out + Z2 @ WoutT. 32x64 tile, grid (8,32).
template<int MODE>
__global__ __launch_bounds__(256, 1)
void gemm_lds(const short* __restrict__ Ag, const short* __restrict__ Whg,
              const short* __restrict__ Wlg, const float* __restrict__ e0,
              float* __restrict__ outp)
{
  constexpr int BM  = MODE == 0 ? 128 : 32;
  constexpr int BN  = MODE == 0 ? 128 : 64;
  constexpr int MR  = MODE == 0 ? 4 : 1;
  constexpr int NR  = MODE == 0 ? 4 : 2;
  constexpr int KT  = MODE == 0 ? 16 : 32;     // K-steps of 64
  constexpr int AK  = MODE == 0 ? 4096 : 2048; // row length of A and W^T
  constexpr int APW = BM / 32;                 // A global_load_lds per wave
  constexpr int WPW = BN / 32;

  __shared__ __align__(16) short As[BM * 64];
  __shared__ __align__(16) short Wh[BN * 64];
  __shared__ __align__(16) short Wl[MODE == 0 ? BN * 64 : 8];

  const int tid = threadIdx.x, lane = tid & 63, wv = tid >> 6;
  const int lr = lane & 15, hl = lane >> 4;
  const int rA = lane >> 3, ts = lane & 7;

  int m0, n0, kz;
  if constexpr (MODE == 0) {                   // XCD-chunked swizzle (512 % 8 == 0)
    const int bid = blockIdx.x;
    const int swz = (bid & 7) * 64 + (bid >> 3);
    m0 = (swz & 7) * BM;
    n0 = ((swz >> 3) & 15) * BN;
    kz = swz >> 7;
  } else {
    m0 = blockIdx.y * BM; n0 = blockIdx.x * BN; kz = 0;
  }
  const int kb = kz * 1024;
  float* P = (MODE == 0) ? outp + (size_t)kz * (Bq * Hq) : outp;

  const int wm = (wv >> 1) * (MR * 16);
  const int wn = (wv & 1) * (NR * 16);

  f32x4 acc[MR][NR];
#pragma unroll
  for (int mi = 0; mi < MR; ++mi)
#pragma unroll
    for (int ni = 0; ni < NR; ++ni) acc[mi][ni] = (f32x4){0.f, 0.f, 0.f, 0.f};

  // global source is seg-XOR-swizzled so linear global_load_lds dest + swizzled
  // ds_read form a consistent involution (guide G21 / m173 pattern)
  auto STAGE = [&](int kt) {
    const int k = kb + kt * 64;
#pragma unroll
    for (int q = 0; q < APW; ++q) {
      const int slot = wv * APW + q;
      const int r = slot * 8 + rA;
      const int s = ts ^ (r & 7);
      gl_lds16(Ag + (m0 + r) * AK + k + s * 8, &As[slot * 512]);
    }
#pragma unroll
    for (int q = 0; q < WPW; ++q) {
      const int slot = wv * WPW + q;
      const int r = slot * 8 + rA;
      const int s = ts ^ (r & 7);
      gl_lds16(Whg + (n0 + r) * AK + k + s * 8, &Wh[slot * 512]);
      if constexpr (MODE == 0)
        gl_lds16(Wlg + (n0 + r) * AK + k + s * 8, &Wl[slot * 512]);
    }
  };

  STAGE(0);
  for (int kt = 0; kt < KT; ++kt) {
    __syncthreads();                            // drains vmcnt(0): stage visible
#pragma unroll
    for (int ks = 0; ks < 2; ++ks) {
      bf16x8 af[MR];
#pragma unroll
      for (int mi = 0; mi < MR; ++mi) {
        const int r = wm + mi * 16 + lr;
        af[mi] = *(const bf16x8*)&As[r * 64 + (((ks * 4 + hl) ^ (r & 7)) << 3)];
      }
#pragma unroll
      for (int ni = 0; ni < NR; ++ni) {
        const int rn = wn + ni * 16 + lr;
        const int sp = (((ks * 4 + hl) ^ (rn & 7)) << 3);
        const bf16x8 bh = *(const bf16x8*)&Wh[rn * 64 + sp];
#pragma unroll
        for (int mi = 0; mi < MR; ++mi)
          acc[mi][ni] = __builtin_amdgcn_mfma_f32_16x16x32_bf16(af[mi], bh, acc[mi][ni], 0, 0, 0);
        if constexpr (MODE == 0) {
          const bf16x8 bl = *(const bf16x8*)&Wl[rn * 64 + sp];
#pragma unroll
          for (int mi = 0; mi < MR; ++mi)
            acc[mi][ni] = __builtin_amdgcn_mfma_f32_16x16x32_bf16(af[mi], bl, acc[mi][ni], 0, 0, 0);
        }
      }
    }
    __syncthreads();
    if (kt + 1 < KT) STAGE(kt + 1);
  }

  // epilogue: C/D frag layout col=lane&15, row=(lane>>4)*4+reg
#pragma unroll
  for (int mi = 0; mi < MR; ++mi)
#pragma unroll
    for (int ni = 0; ni < NR; ++ni)
#pragma unroll
      for (int j = 0; j < 4; ++j) {
        const int m = m0 + wm + mi * 16 + hl * 4 + j;
        const int n = n0 + wn + ni * 16 + lr;
        if constexpr (MODE == 0) {
          P[m * Hq + n] = acc[mi][ni][j];
        } else {
          const int idx = m * NOUTq + n;
          outp[idx] = DECAYF * e0[idx] + acc[mi][ni][j];
        }
      }
}

// combine partials + LIF elementwise; also emit new_z as bf16 for GEMM2
__global__ __launch_bounds__(256)
void lif_epi(const f32x4* __restrict__ Pp, const f32x4* __restrict__ vin,
             const f32x4* __restrict__ zin, const f32x4* __restrict__ rin,
             float* __restrict__ dout, short* __restrict__ z2)
{
  const int i = blockIdx.x * 256 + threadIdx.x;          // 2048 blocks x 256 = exact
  const f32x4 it = Pp[i] + Pp[i + 524288] + Pp[i + 2 * 524288] + Pp[i + 3 * 524288];
  const f32x4 vo = vin[i], zo = zin[i], ro = rin[i];
  f32x4 nv, nz, nr, dz;
  s16x4 zb;
#pragma unroll
  for (int j = 0; j < 4; ++j) {
    const float v1 = DECAYF * vo[j] + it[j] - zo[j] * THRF;
    const float vs = (v1 - THRF) / THRF;
    const bool refr = ro[j] > 0.1f;
    const float z1 = (refr || !(vs > 0.0f)) ? 0.0f : 1.0f;
    nv[j] = v1; nz[j] = z1;
    nr[j] = fminf(fmaxf(ro[j] + 5.0f * z1 - 1.0f, 0.0f), 5.0f);
    dz[j] = refr ? 0.0f : (fmaxf(0.3f * (1.0f - fabsf(vs)), 0.0f) / THRF);
    zb[j] = (short)cvt_bf16(z1);
  }
  ((f32x4*)(dout + OFF_V))[i] = nv;
  ((f32x4*)(dout + OFF_Z))[i] = nz;
  ((f32x4*)(dout + OFF_R))[i] = nr;
  ((f32x4*)(dout + OFF_DZ))[i] = dz;
  ((s16x4*)z2)[i] = zb;
}

// ---------------- fallback path (round-1, used if ws too small) ----------------

template<int MODE>
__global__ __launch_bounds__(256, 1)
void fb_gemm(const float* __restrict__ A0g, const float* __restrict__ A1g,
             const float* __restrict__ W0g, const float* __restrict__ W1g,
             const float* __restrict__ e0, const float* __restrict__ e1,
             const float* __restrict__ e2, float* __restrict__ dout)
{
  constexpr int BM = (MODE == 0) ? 64 : 32;
  constexpr int BN = (MODE == 0) ? 128 : 64;
  constexpr int BK = 64;
  constexpr int LDA = BK + 8;
  constexpr int MR = (MODE == 0) ? 2 : 1;
  constexpr int NR = (MODE == 0) ? 4 : 2;
  constexpr int WM = MR * 16, WN = NR * 16;
  constexpr int KT = (MODE == 0) ? 64 : 32;
  constexpr int Nmat = (MODE == 0) ? Hq : NOUTq;
  constexpr int QA = BM / 16;
  constexpr int QW = (16 * BN) / 256;
  constexpr int KSH = (MODE == 0) ? 7 : 6;
  constexpr int KSTEP = (MODE == 0) ? 2 : 4;

  __shared__ __align__(16) short As[BM * LDA];
  __shared__ __align__(16) short Wh[BN * LDA];
  __shared__ __align__(16) short Wl[((MODE == 0) ? BN : 1) * LDA];

  const int tid  = threadIdx.x;
  const int lane = tid & 63;
  const int wave = tid >> 6;
  const int lr = lane & 15, hl = lane >> 4;
  const int wmOff = (wave >> 1) * WM;
  const int wnOff = (wave & 1) * WN;
  const int m0 = blockIdx.y * BM;
  const int n0 = blockIdx.x * BN;
  const int arow = tid >> 4, ac4 = tid & 15;
  const int wn = tid & (BN - 1);

  f32x4 aR[QA];
  float wR[QW][4];
  f32x4 acc[MR][NR];
#pragma unroll
  for (int mi = 0; mi < MR; ++mi)
#pragma unroll
    for (int ni = 0; ni < NR; ++ni)
      acc[mi][ni] = (f32x4){0.f, 0.f, 0.f, 0.f};

  auto LOAD = [&](int kt) {
    const float* Ag = A0g; const float* Wg = W0g; int k0 = kt * BK;
    if (MODE == 0 && kt >= 32) { Ag = A1g; Wg = W1g; k0 = (kt - 32) * BK; }
#pragma unroll
    for (int q = 0; q < QA; ++q)
      aR[q] = *(const f32x4*)&Ag[(m0 + arow + q * 16) * 2048 + k0 + ac4 * 4];
#pragma unroll
    for (int p = 0; p < QW; ++p) {
      const int kq = (tid >> KSH) + p * KSTEP;
#pragma unroll
      for (int i = 0; i < 4; ++i)
        wR[p][i] = Wg[(k0 + kq * 4 + i) * Nmat + n0 + wn];
    }
  };

  auto STORE = [&]() {
#pragma unroll
    for (int q = 0; q < QA; ++q) {
      s16x4 hv;
#pragma unroll
      for (int j = 0; j < 4; ++j) hv[j] = (short)cvt_bf16(aR[q][j]);
      *(s16x4*)&As[(arow + q * 16) * LDA + ac4 * 4] = hv;
    }
#pragma unroll
    for (int p = 0; p < QW; ++p) {
      const int kq = (tid >> KSH) + p * KSTEP;
      s16x4 hh, ll;
#pragma unroll
      for (int i = 0; i < 4; ++i) {
        const float w = wR[p][i];
        const unsigned short h = cvt_bf16(w);
        hh[i] = (short)h;
        if (MODE == 0) {
          const float hf = __uint_as_float(((unsigned)h) << 16);
          ll[i] = (short)cvt_bf16(w - hf);
        }
      }
      *(s16x4*)&Wh[wn * LDA + kq * 4] = hh;
      if (MODE == 0) *(s16x4*)&Wl[wn * LDA + kq * 4] = ll;
    }
  };

  LOAD(0);
  for (int kt = 0; kt < KT; ++kt) {
    __syncthreads();
    STORE();
    __syncthreads();
    if (kt + 1 < KT) LOAD(kt + 1);
#pragma unroll
    for (int ks = 0; ks < 2; ++ks) {
      bf16x8 af[MR];
#pragma unroll
      for (int mi = 0; mi < MR; ++mi)
        af[mi] = *(const bf16x8*)&As[(wmOff + mi * 16 + lr) * LDA + ks * 32 + hl * 8];
#pragma unroll
      for (int ni = 0; ni < NR; ++ni) {
        const bf16x8 bh = *(const bf16x8*)&Wh[(wnOff + ni * 16 + lr) * LDA + ks * 32 + hl * 8];
#pragma unroll
        for (int mi = 0; mi < MR; ++mi)
          acc[mi][ni] = __builtin_amdgcn_mfma_f32_16x16x32_bf16(af[mi], bh, acc[mi][ni], 0, 0, 0);
        if (MODE == 0) {
          const bf16x8 bl = *(const bf16x8*)&Wl[(wnOff + ni * 16 + lr) * LDA + ks * 32 + hl * 8];
#pragma unroll
          for (int mi = 0; mi < MR; ++mi)
            acc[mi][ni] = __builtin_amdgcn_mfma_f32_16x16x32_bf16(af[mi], bl, acc[mi][ni], 0, 0, 0);
        }
      }
    }
  }

#pragma unroll
  for (int mi = 0; mi < MR; ++mi) {
#pragma unroll
    for (int ni = 0; ni < NR; ++ni) {
#pragma unroll
      for (int j = 0; j < 4; ++j) {
        const int m = m0 + wmOff + mi * 16 + hl * 4 + j;
        const int n = n0 + wnOff + ni * 16 + lr;
        if (MODE == 0) {
          const int idx = m * Hq + n;
          const float it = acc[mi][ni][j];
          const float vold = e0[idx];
          const float zold = e1[idx];
          const float rold = e2[idx];
          const float nv = DECAYF * vold + it - zold * THRF;
          const float vs = (nv - THRF) / THRF;
          const bool refr = rold > 0.1f;
          const float nz = (refr || !(vs > 0.0f)) ? 0.0f : 1.0f;
          const float nr = fminf(fmaxf(rold + 5.0f * nz - 1.0f, 0.0f), 5.0f);
          const float dz = refr ? 0.0f : (fmaxf(0.3f * (1.0f - fabsf(vs)), 0.0f) / THRF);
          dout[OFF_V + idx] = nv;
          dout[OFF_Z + idx] = nz;
          dout[OFF_R + idx] = nr;
          dout[OFF_DZ + idx] = dz;
        } else {
          const int idx = m * NOUTq + n;
          dout[OFF_OUT + idx] = DECAYF * e0[idx] + acc[mi][ni][j];
        }
      }
    }
  }
}

__global__ __launch_bounds__(256)
void fb_trace(const float4* __restrict__ tin, const float4* __restrict__ ins,
              const float4* __restrict__ trec, const float4* __restrict__ zin,
              float4* __restrict__ o1, float4* __restrict__ o2)
{
  const int n4 = (Bq * 2048) / 4;
  for (int i = blockIdx.x * blockDim.x + threadIdx.x; i < n4; i += gridDim.x * blockDim.x) {
    const float4 a = tin[i], b = ins[i];
    float4 u;
    u.x = a.x * DECAYF + b.x; u.y = a.y * DECAYF + b.y;
    u.z = a.z * DECAYF + b.z; u.w = a.w * DECAYF + b.w;
    o1[i] = u;
    const float4 c = trec[i], d = zin[i];
    float4 w;
    w.x = c.x * DECAYF + d.x; w.y = c.y * DECAYF + d.y;
    w.z = c.z * DECAYF + d.z; w.w = c.w * DECAYF + d.w;
    o2[i] = w;
  }
}

extern "C" void kernel_launch(void* const* d_in, const int* in_sizes, int n_in,
                              void* d_out, int out_size, void* d_ws, size_t ws_size,
                              hipStream_t stream) {
  const float* inputs = (const float*)d_in[0];
  const float* v      = (const float*)d_in[1];
  const float* z      = (const float*)d_in[2];
  const float* r      = (const float*)d_in[3];
  const float* outp   = (const float*)d_in[4];
  const float* tin    = (const float*)d_in[5];
  const float* trec   = (const float*)d_in[6];
  const float* w_in   = (const float*)d_in[7];
  const float* w_rec  = (const float*)d_in[8];
  const float* w_out  = (const float*)d_in[9];
  float* out = (float*)d_out;

  if (ws_size >= WS_NEED) {
    char* ws = (char*)d_ws;
    short* Acomb = (short*)(ws + WS_ACOMB);
    short* Whi   = (short*)(ws + WS_WHI);
    short* Wlo   = (short*)(ws + WS_WLO);
    short* WoutT = (short*)(ws + WS_WOUTT);
    float* P     = (float*)(ws + WS_P);
    short* Z2    = (short*)(ws + WS_Z2);

    trace_convA<<<2048, 256, 0, stream>>>((const f32x4*)tin, (const f32x4*)inputs,
                                          (const f32x4*)trec, (const f32x4*)z,
                                          (f32x4*)(out + OFF_TIN), (f32x4*)(out + OFF_TREC), Acomb);
    convW<<<2304, 256, 0, stream>>>(w_in, w_rec, w_out, Whi, Wlo, WoutT);
    gemm_lds<0><<<512, 256, 0, stream>>>(Acomb, Whi, Wlo, nullptr, P);
    lif_epi<<<2048, 256, 0, stream>>>((const f32x4*)P, (const f32x4*)v, (const f32x4*)z,
                                      (const f32x4*)r, out, Z2);
    gemm_lds<1><<<dim3(8, 32), 256, 0, stream>>>(Z2, WoutT, nullptr, outp, out + OFF_OUT);
  } else {
    fb_trace<<<2048, 256, 0, stream>>>((const float4*)tin, (const float4*)inputs,
                                       (const float4*)trec, (const float4*)z,
                                       (float4*)(out + OFF_TIN), (float4*)(out + OFF_TREC));
    fb_gemm<0><<<dim3(16, 16), 256, 0, stream>>>(inputs, z, w_in, w_rec, v, z, r, out);
    fb_gemm<1><<<dim3(8, 32), 256, 0, stream>>>(out + OFF_Z, nullptr, w_out, nullptr,
                                                outp, nullptr, nullptr, out);
  }
}